// Round 2
// 806.264 us; speedup vs baseline: 1.0327x; 1.0327x over previous
//
#include <hip/hip_runtime.h>

// Space-to-depth reorg (stride 2), fp32.
// in : (32, 64, 256, 256)   out: (32, 256, 128, 128)
// out[b, i*4 + l*2 + m, oy, ox] = x[b, i, 2*oy + l, 2*ox + m]
//
// Dense-instruction variant:
//   Each thread owns ONE float4 chunk (cols 4q..4q+3) from EACH of the two
//   input rows of an oy-pair (y = 2*oy and 2*oy+1).
//   - Loads: lane q in [0,64) -> wave covers one full 1 KB input row per
//     global_load_dwordx4, fully dense, single segment.
//   - Stores: 4 x float2 (dwordx2), one per output channel c0..c0+3; each
//     instruction writes one full 512 B output row (ox = 2q, 2q+1 across the
//     wave), fully dense, single segment.
//   Every cache line is touched exactly once -> nontemporal hints on both
//   sides to keep the 4 GB stream from churning L2/LLC.

typedef float f32x4 __attribute__((ext_vector_type(4)));
typedef float f32x2 __attribute__((ext_vector_type(2)));

constexpr int B  = 32;
constexpr int C  = 64;
constexpr int H  = 256;
constexpr int W  = 256;
constexpr int OH = H / 2;   // 128
constexpr int OW = W / 2;   // 128

__global__ __launch_bounds__(256) void reorg_kernel(const float* __restrict__ x,
                                                    float* __restrict__ out) {
    const unsigned t = blockIdx.x * blockDim.x + threadIdx.x;

    const unsigned q  = t & 63u;               // float4 chunk within a row (W/4 = 64)
    const unsigned oy = (t >> 6) & (OH - 1u);  // output row
    const unsigned p  = t >> 13;               // plane = b*C + i
    const unsigned i  = p & (C - 1u);
    const unsigned b  = p >> 6;                // / C

    // Two dense row loads (y = 2*oy, 2*oy+1).
    const size_t rbase = ((size_t)p * H + 2u * oy) * W + 4u * q;
    const f32x4 f0 = __builtin_nontemporal_load(
        reinterpret_cast<const f32x4*>(x + rbase));        // row 2*oy   (l = 0)
    const f32x4 f1 = __builtin_nontemporal_load(
        reinterpret_cast<const f32x4*>(x + rbase + W));    // row 2*oy+1 (l = 1)

    // Four dense 512 B row stores, one per channel c0..c0+3.
    const unsigned c0 = i * 4u;
    const size_t plane = (size_t)OH * OW;                  // 16384 floats
    const size_t obase =
        (((size_t)(b * (C * 4) + c0) * OH) + oy) * OW + 2u * q;

    f32x2 s;
    s.x = f0.x; s.y = f0.z;   // l=0, m=0
    __builtin_nontemporal_store(s, reinterpret_cast<f32x2*>(out + obase));
    s.x = f0.y; s.y = f0.w;   // l=0, m=1
    __builtin_nontemporal_store(s, reinterpret_cast<f32x2*>(out + obase + plane));
    s.x = f1.x; s.y = f1.z;   // l=1, m=0
    __builtin_nontemporal_store(s, reinterpret_cast<f32x2*>(out + obase + 2 * plane));
    s.x = f1.y; s.y = f1.w;   // l=1, m=1
    __builtin_nontemporal_store(s, reinterpret_cast<f32x2*>(out + obase + 3 * plane));
}

extern "C" void kernel_launch(void* const* d_in, const int* in_sizes, int n_in,
                              void* d_out, int out_size, void* d_ws, size_t ws_size,
                              hipStream_t stream) {
    const float* x = (const float*)d_in[0];
    float* out = (float*)d_out;

    // One thread per (plane, oy, chunk): 32*64 * 128 * 64 = 16,777,216
    const unsigned total_threads = (unsigned)(B * C * OH * (W / 4));
    const unsigned block = 256;
    const unsigned grid = total_threads / block;           // 65,536

    reorg_kernel<<<grid, block, 0, stream>>>(x, out);
}

// Round 3
// 795.069 us; speedup vs baseline: 1.0472x; 1.0141x over previous
//
#include <hip/hip_runtime.h>

// Space-to-depth reorg (stride 2), fp32.
// in : (32, 64, 256, 256)   out: (32, 256, 128, 128)
// out[b, i*4 + l*2 + m, oy, ox] = x[b, i, 2*oy + l, 2*ox + m]
//
// Copy-shape variant (LDS-staged):
//   Block = 256 threads = 4 waves, handles 4 input rows (one oy-pair) of one
//   plane: 4 KB in -> 4 KB out.
//   - Load: wave r reads input row y0+r as one dense global_load_dwordx4
//     (64 lanes x 16 B = full 1 KB row, single segment).
//   - LDS: de-interleave even/odd columns via 2x ds_write_b64 (dense, 2-way
//     = free), barrier, then ds_read_b128 (dense, conflict-free).
//   - Store: wave j writes output channel c0+j rows {2*oyp, 2*oyp+1} as one
//     dense global_store_dwordx4 (64 lanes x 16 B = 1 KB, single segment).
//   Per thread: 1 load dwordx4 + 1 store dwordx4 -> identical VMEM profile
//   to the 6.29 TB/s float4 copy. NT hints both sides (zero reuse).

typedef float f32x4 __attribute__((ext_vector_type(4)));
typedef float f32x2 __attribute__((ext_vector_type(2)));

constexpr int B  = 32;
constexpr int C  = 64;
constexpr int H  = 256;
constexpr int W  = 256;
constexpr int OH = H / 2;   // 128
constexpr int OW = W / 2;   // 128

__global__ __launch_bounds__(256) void reorg_kernel(const float* __restrict__ x,
                                                    float* __restrict__ out) {
    __shared__ float ev[4][128];   // ev[r][c] = x[plane, y0+r, 2c]
    __shared__ float od[4][128];   // od[r][c] = x[plane, y0+r, 2c+1]

    const unsigned blk = blockIdx.x;
    const unsigned oyp = blk & 63u;     // group of 4 input rows / 2 output rows
    const unsigned p   = blk >> 6;      // plane = b*C + i
    const unsigned t   = threadIdx.x;
    const unsigned q   = t & 63u;       // lane
    const unsigned r   = t >> 6;        // wave id = input row (load), channel j (store)

    // ---- load: wave r reads input row y0+r, fully dense 1 KB ----
    const size_t ibase = ((size_t)p * H + 4u * oyp + r) * W + 4u * q;
    const f32x4 f = __builtin_nontemporal_load(
        reinterpret_cast<const f32x4*>(x + ibase));

    // ---- de-interleave into LDS ----
    f32x2 e; e.x = f.x; e.y = f.z;      // cols 4q, 4q+2
    f32x2 o; o.x = f.y; o.y = f.w;      // cols 4q+1, 4q+3
    *reinterpret_cast<f32x2*>(&ev[r][2u * q]) = e;
    *reinterpret_cast<f32x2*>(&od[r][2u * q]) = o;
    __syncthreads();

    // ---- store: wave j = r writes channel c0+j, rows 2*oyp..2*oyp+1 (1 KB) ----
    const unsigned j  = r;
    const unsigned l  = j >> 1;
    const unsigned m  = j & 1u;
    const unsigned hi = q >> 5;         // which output row of the pair
    const unsigned k  = q & 31u;        // float4 index within the 512 B row
    const float* src = (m ? od : ev)[2u * hi + l] + 4u * k;
    const f32x4 g = *reinterpret_cast<const f32x4*>(src);

    const unsigned i = p & (C - 1u);
    const unsigned b = p >> 6;
    const size_t obase =
        (((size_t)(b * (C * 4) + i * 4u + j) * OH) + 2u * oyp + hi) * OW + 4u * k;
    __builtin_nontemporal_store(g, reinterpret_cast<f32x4*>(out + obase));
}

extern "C" void kernel_launch(void* const* d_in, const int* in_sizes, int n_in,
                              void* d_out, int out_size, void* d_ws, size_t ws_size,
                              hipStream_t stream) {
    const float* x = (const float*)d_in[0];
    float* out = (float*)d_out;

    // One block per (plane, 4-row group): 32*64 * 64 = 131,072 blocks.
    const unsigned grid = (unsigned)(B * C * (H / 4));
    const unsigned block = 256;

    reorg_kernel<<<grid, block, 0, stream>>>(x, out);
}